// Round 5
// baseline (5062.346 us; speedup 1.0000x reference)
//
#include <hip/hip_runtime.h>
#include <cstdint>

// VAN checkerboard sampler, LEVEL=0 (odd,odd positions), B=4096, L=16, H=32, K=5.
// One 1024-thread block per batch element; all 64 autoregressive steps in-kernel.
// w2 lives in registers (25 floats per (oc,ic) thread); x / h1-tile / w1 / w3 in LDS.
// Deterministic reductions only (graph replay must revalidate bit-identically).
//
// R5: 2 blocks/CU (launch_bounds 1024,8; R3/R4: occupancy 47->90%) with phase 2 in
// THREE passes so the arch-VGPR live set fits the 32-arch allocation the compiler
// chooses under the 64-unified budget:
//   pass A: dy {0,1} (10 accs, rows tr 0..5)
//   pass B: dy {2,3} (10 accs, rows tr 2..7)
//   pass C: dy {4}   ( 5 accs, rows tr 4..8)
// R4 (2-pass, 15-acc peak) still ran ~1.9x essential VALU: 32 arch VGPRs forced
// v_accvgpr_read/write around nearly every FMA (49 peak live). With peak ~24 arch
// live, w2r[25] can sit in AGPRs as read-only operands (cheap), acc/rows in arch.
// Bit-exact: per-element fma chain order (tr asc == ky asc, kx asc) identical;
// merge shfl, s_buf addresses, phase-3 sum order unchanged.

struct U2 { uint32_t x, y; };

// JAX Threefry-2x32 (20 rounds), matches jax/_src/prng.py
__device__ __forceinline__ U2 tf2x32(uint32_t k0, uint32_t k1, uint32_t x0, uint32_t x1) {
  uint32_t k2 = k0 ^ k1 ^ 0x1BD11BDAu;
#define TFROT(r) { x0 += x1; x1 = (x1 << (r)) | (x1 >> (32 - (r))); x1 ^= x0; }
  x0 += k0; x1 += k1;
  TFROT(13) TFROT(15) TFROT(26) TFROT(6)
  x0 += k1; x1 += k2 + 1u;
  TFROT(17) TFROT(29) TFROT(16) TFROT(24)
  x0 += k2; x1 += k0 + 2u;
  TFROT(13) TFROT(15) TFROT(26) TFROT(6)
  x0 += k0; x1 += k1 + 3u;
  TFROT(17) TFROT(29) TFROT(16) TFROT(24)
  x0 += k1; x1 += k2 + 4u;
  TFROT(13) TFROT(15) TFROT(26) TFROT(6)
  x0 += k2; x1 += k0 + 5u;
#undef TFROT
  return {x0, x1};
}

__device__ __forceinline__ float lrelu(float v) { return fmaxf(v, 0.1f * v); }

__launch_bounds__(1024, 8)
__global__ void van_kernel(const float* __restrict__ gx,
                           const float* __restrict__ gw1, const float* __restrict__ gb1,
                           const float* __restrict__ gw2, const float* __restrict__ gb2,
                           const float* __restrict__ gw3, const float* __restrict__ gb3,
                           float* __restrict__ out, int B) {
  // x field with +/-6 circular halo: array row t <-> field row (t-6)&15
  __shared__ __align__(16) float s_xf[28 * 28];
  __shared__ __align__(16) float s_h1[32][9][12];   // h1 tile, row pitch 12 (16B aligned rows)
  __shared__ __align__(16) float s_w1[800];
  __shared__ __align__(16) float s_w3[800];
  __shared__ __align__(16) float s_buf[8][800];     // reduction tree buffers
  __shared__ float s_b1[32], s_b2[32];
  __shared__ float s_u[64];                          // per-step uniforms for this batch elem
  __shared__ float s_c3[16];                         // per-wave conv3 partials

  const int tid  = threadIdx.x;
  const int bg   = blockIdx.x;
  const int lane = tid & 63;
  const int wv   = tid >> 6;
  const int oc   = tid & 31;   // conv2 out-channel of this thread
  const int ic   = tid >> 5;   // conv2 in-channel of this thread

  // ---------------- init ----------------
  const float b3v = gb3[0];
  float w2r[25];
  {
    const float* p = gw2 + (oc * 32 + ic) * 25;   // w2[oc][ic][ky][kx]
    #pragma unroll
    for (int k = 0; k < 25; ++k) w2r[k] = p[k];
  }
  if (tid < 800) { s_w1[tid] = gw1[tid]; s_w3[tid] = gw3[tid]; }
  if (tid < 32)  { s_b1[tid] = gb1[tid]; s_b2[tid] = gb2[tid]; }
  if (tid < 784) {
    int rr = tid / 28, cc = tid - rr * 28;
    int fy = (rr - 6) & 15, fx = (cc - 6) & 15;
    s_xf[tid] = gx[bg * 256 + fy * 16 + fx];
  }
  if (tid < 64) {
    // jax_threefry_partitionable=True conventions:
    // key_s = threefry(root=(0,42), (0, s)); bits(b) = x^y of threefry(key_s, (0, b))
    U2 key = tf2x32(0u, 42u, 0u, (uint32_t)tid);
    U2 tt  = tf2x32(key.x, key.y, 0u, (uint32_t)bg);
    uint32_t bits = tt.x ^ tt.y;
    s_u[tid] = __uint_as_float(0x3F800000u | (bits >> 9)) - 1.0f;
  }
  float logq = 0.f;   // only thread 0's copy is meaningful
  __syncthreads();

  #pragma unroll 1
  for (int s = 0; s < 64; ++s) {
    const int i = 2 * (s >> 3) + 1;
    const int j = 2 * (s & 7) + 1;

    // ---- phase 1: h1 tile (9x9x32) from x; tile (r,c) <-> field (i-4+r, j-4+c) ----
    if (tid < 288) {
      const int t_ic = tid / 9;
      const int r    = tid - t_ic * 9;
      const float bb = s_b1[t_ic];
      float a[9];
      #pragma unroll
      for (int c = 0; c < 9; ++c) a[c] = bb;
      #pragma unroll
      for (int ky = 0; ky < 5; ++ky) {
        const float* xr = &s_xf[(i + r + ky) * 28 + j];   // field row i-6+r+ky, cols j-6..j+6
        float xv[13];
        #pragma unroll
        for (int m = 0; m < 13; ++m) xv[m] = xr[m];
        #pragma unroll
        for (int kx = 0; kx < 5; ++kx) {
          const float w = s_w1[t_ic * 25 + ky * 5 + kx];
          #pragma unroll
          for (int c = 0; c < 9; ++c) a[c] = fmaf(xv[c + kx], w, a[c]);
        }
      }
      #pragma unroll
      for (int c = 0; c < 9; ++c) s_h1[t_ic][r][c] = lrelu(a[c]);
    }
    __syncthreads();

    // ---- phase 2: conv2 at 25 positions, 3 passes (10/10/5 accs) ----
    // Per-pass: all waves compute; wv>=8 bank into s_buf; sync; wv<8 add in.
    // Pass p-ranges are disjoint so pass N+1's banking can't race pass N's adds.
#define CONV2_PASS(DYLO, DYHI, TRLO, TRHI, NACC)                                   \
    {                                                                              \
      float acc[NACC];                                                             \
      _Pragma("unroll")                                                            \
      for (int p = 0; p < (NACC); ++p) acc[p] = 0.f;                               \
      _Pragma("unroll")                                                            \
      for (int tr = (TRLO); tr <= (TRHI); ++tr) {                                  \
        const float4* rp = (const float4*)(&s_h1[ic][tr][0]);                      \
        const float4 ra = rp[0], rb = rp[1];                                       \
        const float r8 = s_h1[ic][tr][8];                                          \
        const float row[9] = {ra.x, ra.y, ra.z, ra.w, rb.x, rb.y, rb.z, rb.w, r8}; \
        _Pragma("unroll")                                                          \
        for (int dy = (DYLO); dy <= (DYHI); ++dy) {                                \
          const int ky = tr - dy;                                                  \
          if (ky < 0 || ky > 4) continue;   /* folds at compile time */            \
          _Pragma("unroll")                                                        \
          for (int kx = 0; kx < 5; ++kx) {                                         \
            const float w = w2r[ky * 5 + kx];                                      \
            _Pragma("unroll")                                                      \
            for (int dx = 0; dx < 5; ++dx)                                         \
              acc[(dy - (DYLO)) * 5 + dx] = fmaf(row[dx + kx], w,                  \
                                                 acc[(dy - (DYLO)) * 5 + dx]);     \
          }                                                                        \
        }                                                                          \
      }                                                                            \
      _Pragma("unroll")                                                            \
      for (int p = 0; p < (NACC); ++p) acc[p] += __shfl_xor(acc[p], 32, 64);       \
      if (wv >= 8 && lane < 32) {                                                  \
        _Pragma("unroll")                                                          \
        for (int p = 0; p < (NACC); ++p)                                           \
          s_buf[wv - 8][((DYLO) * 5 + p) * 32 + lane] = acc[p];                    \
      }                                                                            \
      __syncthreads();                                                             \
      if (wv < 8 && lane < 32) {                                                   \
        _Pragma("unroll")                                                          \
        for (int p = 0; p < (NACC); ++p)                                           \
          s_buf[wv][((DYLO) * 5 + p) * 32 + lane] += acc[p];                       \
      }                                                                            \
    }

    CONV2_PASS(0, 1, 0, 5, 10)   // p = 0..9,   rows 0..5
    CONV2_PASS(2, 3, 2, 7, 10)   // p = 10..19, rows 2..7
    CONV2_PASS(4, 4, 4, 8, 5)    // p = 20..24, rows 4..8
#undef CONV2_PASS
    __syncthreads();

    // ---- phase 3: final a2 sum (fixed order), lrelu, conv3 partials ----
    float v3 = 0.f;
    if (tid < 800) {
      float t = 0.f;
      #pragma unroll
      for (int v = 0; v < 8; ++v) t += s_buf[v][tid];
      t += s_b2[tid & 31];
      const float h2 = lrelu(t);
      v3 = h2 * s_w3[(tid & 31) * 25 + (tid >> 5)];   // w3[oc][pos]
    }
    #pragma unroll
    for (int m = 32; m >= 1; m >>= 1) v3 += __shfl_xor(v3, m, 64);
    if (lane == 0) s_c3[wv] = v3;
    __syncthreads();

    // ---- phase 4: sample (thread 0), update x field halo copies ----
    if (tid == 0) {
      float logit = b3v;
      #pragma unroll
      for (int v = 0; v < 16; ++v) logit += s_c3[v];
      const float pr   = 1.f / (1.f + expf(-logit));
      const float u    = s_u[s];
      const float samp = (u < pr) ? 1.f : -1.f;
      const int r1 = i + 6, c1 = j + 6;
      const int r2 = (i < 6) ? i + 22 : ((i >= 10) ? i - 10 : r1);
      const int c2 = (j < 6) ? j + 22 : ((j >= 10) ? j - 10 : c1);
      s_xf[r1 * 28 + c1] = samp; s_xf[r1 * 28 + c2] = samp;
      s_xf[r2 * 28 + c1] = samp; s_xf[r2 * 28 + c2] = samp;
      logq += (samp > 0.f) ? logf(pr + 1e-7f) : logf(1.f - pr + 1e-7f);
    }
    __syncthreads();
  }

  // ---------------- output ----------------
  if (tid < 256)
    out[bg * 256 + tid] = s_xf[((tid >> 4) + 6) * 28 + (tid & 15) + 6];
  if (tid == 0)
    out[B * 256 + bg] = logq;
}

extern "C" void kernel_launch(void* const* d_in, const int* in_sizes, int n_in,
                              void* d_out, int out_size, void* d_ws, size_t ws_size,
                              hipStream_t stream) {
  const float* gx  = (const float*)d_in[0];
  const float* gw1 = (const float*)d_in[1];
  const float* gb1 = (const float*)d_in[2];
  const float* gw2 = (const float*)d_in[3];
  const float* gb2 = (const float*)d_in[4];
  const float* gw3 = (const float*)d_in[5];
  const float* gb3 = (const float*)d_in[6];
  float* out = (float*)d_out;
  const int B = in_sizes[0] / 256;

  hipLaunchKernelGGL(van_kernel, dim3(B), dim3(1024), 0, stream,
                     gx, gw1, gb1, gw2, gb2, gw3, gb3, out, B);
}